// Round 13
// baseline (214.028 us; speedup 1.0000x reference)
//
#include <hip/hip_runtime.h>
#include <hip/hip_bf16.h>

#define N_PTS 12288
#define DIM   64
#define KSEL  16
#define EPS_F 1e-5f
#define TMARGIN 1.5f   // >= 2x bf16 cross-pair screen noise (~0.7); was 2.0

typedef __bf16 bf16x8 __attribute__((ext_vector_type(8)));
typedef float  f32x4  __attribute__((ext_vector_type(4)));

// Hand-rolled grid barrier (proven r7-r12; ~40us cheaper than cooperative
// launch). Safe: grid=256, 1 block/CU, co-resident by construction.
__device__ __forceinline__ void grid_sync(int* bar)
{
    __syncthreads();
    if (threadIdx.x == 0) {
        __hip_atomic_fetch_add(bar, 1, __ATOMIC_RELEASE, __HIP_MEMORY_SCOPE_AGENT);
        while (__hip_atomic_load(bar, __ATOMIC_ACQUIRE, __HIP_MEMORY_SCOPE_AGENT)
               < (int)gridDim.x)
            __builtin_amdgcn_s_sleep(2);
    }
    __syncthreads();
}

template<int CVN>
__device__ __forceinline__ void rank_core(const unsigned* __restrict__ drow,
                                          int S, int l32, int* __restrict__ fj)
{
    unsigned cv[CVN]; int rk[CVN];
    #pragma unroll
    for (int t = 0; t < CVN; ++t) {
        cv[t] = (t * 32 + l32 < S) ? drow[t * 32 + l32] : 0xFFFFFFFFu;
        rk[t] = 0;
    }
    #pragma unroll 4
    for (int m = 0; m < S; ++m) {
        const unsigned o = drow[m];
        #pragma unroll
        for (int t = 0; t < CVN; ++t) rk[t] += (o < cv[t]) ? 1 : 0;
    }
    #pragma unroll
    for (int t = 0; t < CVN; ++t)
        if (rk[t] < 32 && cv[t] != 0xFFFFFFFFu)
            fj[rk[t]] = (int)(cv[t] & 0x3FFFu);
}

// ---------------------------------------------------------------------------
// Round-7/12 structure (measured optimum: mega 154us / 200us total) with two
// certified threshold trims (survivor-rank model: ~1.2-1.7us per rank/row):
//  (a) TMARGIN 2.0 -> 1.5 (still >= 2x worst-case bf16 screen noise ~0.7);
//  (b) P1 keeps TOP-3 per segment (96-value pool) instead of top-2 -- kills
//      the ~1-1.5-rank pool-collision inflation of the 17th order statistic.
// Both strictly tighten T; certification chain (pool17 >= sample17 >=
// (sample-sans-self)16 >= d16) unchanged. All else identical to r12.
// ---------------------------------------------------------------------------
__global__ __launch_bounds__(512) void mega_kernel(
    const float* __restrict__ coords,
    const float* __restrict__ pot,
    float* __restrict__ s1,
    float* __restrict__ sx,
    int* __restrict__ bar,
    __hip_bfloat16* __restrict__ chi,
    __hip_bfloat16* __restrict__ chiX,
    float* __restrict__ out)
{
    constexpr int ROWS = 48, TIL = 3, CAPP = 8, OCAP = 16;
    constexpr int SEGS = 32;                     // 8 waves x 4 quads
    constexpr int DCAP = SEGS * CAPP + OCAP;     // 272 structural max/row
    constexpr int DPAD = DCAP + 1;               // 273
    constexpr int JSL  = N_PTS / 8;              // 1536
    constexpr int STEPS = JSL / 16;              // 96

    __shared__ float    colsh[8][64];
    __shared__ float    sqs8[8];
    __shared__ float    sqloc[ROWS];
    __shared__ float    pool[ROWS][96];          // [row][seg*3+{0,1,2}]
    __shared__ float    TrowS[ROWS];
    __shared__ unsigned buf[TIL * CAPP * 512];   // 49152 B
    __shared__ int      cntT[TIL][8][4][16];
    __shared__ unsigned dense[ROWS * DPAD];      // 52416 B
    __shared__ unsigned ovf[ROWS][OCAP];
    __shared__ int      ovcnt[ROWS];
    __shared__ int      stotS[ROWS];
    __shared__ int      finj[16][32];
    __shared__ double   refd[16][32];
    __shared__ double   s_inv_den;

    const int tid  = threadIdx.x;
    const int lane = tid & 63;
    const int wave = tid >> 6;                   // 0..7
    const int col  = lane & 15;
    const int quad = lane >> 4;
    const int ibase = (int)blockIdx.x * ROWS;

    // ---------------- phase A: stats for own 48 rows ----------------
    float colsum = 0.f, sqsum = 0.f;
    #pragma unroll 1
    for (int k = 0; k < 6; ++k) {
        const int rl = wave * 6 + k, gr = ibase + rl;
        const float x = coords[gr * DIM + lane];
        chi[gr * DIM + lane] = __float2bfloat16(x);
        colsum += x;
        float p = x * x;
        #pragma unroll
        for (int off = 32; off > 0; off >>= 1) p += __shfl_xor(p, off, 64);
        if (lane == 0) { sqloc[rl] = p; sqsum += p; }
        if (lane < 8) {
            const __hip_bfloat16 h = __float2bfloat16(p);
            const float lo = p - (float)h;
            __hip_bfloat16 v;
            if (lane == 0)      v = h;
            else if (lane == 1) v = __float2bfloat16(lo);
            else if (lane < 4)  v = __float2bfloat16(1.0f);
            else                v = __float2bfloat16(0.0f);
            chiX[gr * 8 + lane] = v;
        }
    }
    colsh[wave][lane] = colsum;
    if (lane == 0) sqs8[wave] = sqsum;
    if (tid < ROWS) ovcnt[tid] = 0;
    __syncthreads();
    if (wave == 0) {
        float c = 0.f;
        #pragma unroll
        for (int w8 = 0; w8 < 8; ++w8) c += colsh[w8][lane];
        atomicAdd(&sx[lane], c);
    }
    if (tid == 0) {
        float t = 0.f;
        #pragma unroll
        for (int w8 = 0; w8 < 8; ++w8) t += sqs8[w8];
        atomicAdd(s1, t);
    }
    grid_sync(bar);                              // chi/chiX + s1/sx final

    if (tid == 0) {
        double S1 = (double)s1[0], m2 = 0.0;
        for (int d = 0; d < DIM; ++d) { double t = (double)sx[d]; m2 += t * t; }
        const double NN = (double)N_PTS;
        s_inv_den = 1.0 / ((2.0 * NN * S1 - 2.0 * m2) / (NN * NN)
                           + 1e-5 + 1e6 / NN + 1e-5);
    }

    // ---------------- B-fragments (3 tiles x {lo, hi, ext}) ----------------
    const bf16x8* cp  = (const bf16x8*)chi;
    const bf16x8* cpX = (const bf16x8*)chiX;
    bf16x8 bA[TIL], bB[TIL], b2[TIL];
    #pragma unroll
    for (int t = 0; t < TIL; ++t) {
        const int it = ibase + t * 16 + col;
        bA[t] = cp[it * 8 + quad];
        bB[t] = cp[it * 8 + quad + 4];
        bf16x8 v;
        #pragma unroll
        for (int e = 0; e < 8; ++e) v[e] = (__bf16)0.0f;
        if (quad == 0) {                         // ext dims 0..3 live in quad 0
            const float bs = sqloc[t * 16 + col] + EPS_F;
            const __bf16 bh = (__bf16)(0.5f * bs);
            const __bf16 bl = (__bf16)(0.5f * bs - (float)bh);
            v[0] = (__bf16)(-0.5f); v[1] = (__bf16)(-0.5f);
            v[2] = (__bf16)(-(float)bh); v[3] = (__bf16)(-(float)bl);
        }
        b2[t] = v;
    }

    const int jw  = wave * JSL;
    const int seg = wave * 4 + quad;             // 0..31

    auto LD = [&](int s, bf16x8& A0, bf16x8& A1, bf16x8& A2) {
        const int ar = jw + s * 16 + col;
        A0 = cp[ar * 8 + quad];
        A1 = cp[ar * 8 + quad + 4];
        A2 = cpX[ar];                            // quads 1-3 killed by b2 zeros
    };
    auto MFMA3 = [&](const bf16x8& A0, const bf16x8& A1, const bf16x8& A2,
                     f32x4 (&acc)[TIL]) {
        #pragma unroll
        for (int t = 0; t < TIL; ++t) {
            f32x4 a = {0.f, 0.f, 0.f, 0.f};
            a = __builtin_amdgcn_mfma_f32_16x16x32_bf16(A0, bA[t], a, 0, 0, 0);
            a = __builtin_amdgcn_mfma_f32_16x16x32_bf16(A1, bB[t], a, 0, 0, 0);
            a = __builtin_amdgcn_mfma_f32_16x16x32_bf16(A2, b2[t], a, 0, 0, 0);
            acc[t] = a;                          // acc = -d2/2
        }
    };

    // ---------------- P1: stride-2 sampled top-3, 4-deep prefetch ----------
    float m0[TIL], m1[TIL], m2a[TIL];
    #pragma unroll
    for (int t = 0; t < TIL; ++t) { m0[t] = -1e30f; m1[t] = -1e30f; m2a[t] = -1e30f; }
    {
        bf16x8 A0[4], A1[4], A2[4];
        #pragma unroll
        for (int p = 0; p < 4; ++p) LD(2 * p, A0[p], A1[p], A2[p]);
        #pragma unroll 1
        for (int k = 0; k < STEPS / 2; k += 4) {
            #pragma unroll
            for (int p = 0; p < 4; ++p) {
                f32x4 acc[TIL];
                MFMA3(A0[p], A1[p], A2[p], acc);
                int sn = 2 * (k + p + 4);
                sn = (sn < STEPS) ? sn : 0;      // harmless reload at the tail
                LD(sn, A0[p], A1[p], A2[p]);
                #pragma unroll
                for (int t = 0; t < TIL; ++t) {
                    #pragma unroll
                    for (int r = 0; r < 4; ++r) {
                        const float da = acc[t][r];
                        const bool g0 = da > m0[t];
                        const bool g1 = da > m1[t];
                        m2a[t] = g1 ? m1[t] : fmaxf(m2a[t], da);
                        m1[t]  = g0 ? m0[t] : fmaxf(m1[t], da);
                        m0[t]  = fmaxf(m0[t], da);
                    }
                }
            }
        }
    }
    #pragma unroll
    for (int t = 0; t < TIL; ++t) {              // three smallest d2 per bucket
        pool[t * 16 + col][seg * 3]     = -2.f * m0[t];
        pool[t * 16 + col][seg * 3 + 1] = -2.f * m1[t];
        pool[t * 16 + col][seg * 3 + 2] = -2.f * m2a[t];
    }
    __syncthreads();

    // T = 17th smallest of 96 pooled d2 (+margin); wave -> rows 6w..6w+5
    #pragma unroll 1
    for (int rr = 0; rr < 6; ++rr) {
        const int row = wave * 6 + rr;
        const float v0 = pool[row][lane];                       // idx = lane
        const float v1 = (lane < 32) ? pool[row][64 + lane] : 1e30f; // idx = 64+lane
        int r0 = 0, r1 = 0;
        #pragma unroll 8
        for (int m = 0; m < 96; ++m) {
            const float o = pool[row][m];
            r0 += (o < v0 || (o == v0 && m < lane)) ? 1 : 0;
            r1 += (o < v1 || (o == v1 && m < 64 + lane)) ? 1 : 0;
        }
        if (r0 == 16) TrowS[row] = v0 + TMARGIN;
        if (r1 == 16) TrowS[row] = v1 + TMARGIN;
    }
    __syncthreads();

    float tthr[TIL];
    #pragma unroll
    for (int t = 0; t < TIL; ++t) tthr[t] = -0.5f * TrowS[t * 16 + col];

    // ---------------- P2: full screen, branch-light epilogue ---------------
    int ct[TIL] = {0, 0, 0};
    {
        bf16x8 A0[4], A1[4], A2[4];
        #pragma unroll
        for (int p = 0; p < 4; ++p) LD(p, A0[p], A1[p], A2[p]);
        #pragma unroll 1
        for (int s = 0; s < STEPS; s += 4) {
            #pragma unroll
            for (int p = 0; p < 4; ++p) {
                f32x4 acc[TIL];
                MFMA3(A0[p], A1[p], A2[p], acc);
                int sn = s + p + 4;
                sn = (sn < STEPS) ? sn : 0;      // harmless reload at the tail
                LD(sn, A0[p], A1[p], A2[p]);

                const int jq = jw + (s + p) * 16 + quad * 4;
                #pragma unroll
                for (int t = 0; t < TIL; ++t) {
                    const float mx = fmaxf(fmaxf(acc[t][0], acc[t][1]),
                                           fmaxf(acc[t][2], acc[t][3]));
                    if (mx > tthr[t]) {          // wave-rare tile gate
                        if (__all(ct[t] <= CAPP - 4)) {
                            // branchless dense push: write@ct, ct += hit;
                            // misses overwritten by the next write.
                            #pragma unroll
                            for (int r = 0; r < 4; ++r) {
                                const float d2 = -2.f * acc[t][r];
                                const unsigned pk =
                                    (__float_as_uint(d2) & 0xFFFFC000u)
                                    | (unsigned)(jq + r);
                                buf[(t * CAPP + ct[t]) * 512 + tid] = pk;
                                ct[t] += (acc[t][r] > tthr[t]) ? 1 : 0;
                            }
                        } else {                 // near-full: careful + ovf
                            #pragma unroll
                            for (int r = 0; r < 4; ++r) {
                                if (acc[t][r] > tthr[t]) {
                                    const float d2 = -2.f * acc[t][r];
                                    const unsigned pk =
                                        (__float_as_uint(d2) & 0xFFFFC000u)
                                        | (unsigned)(jq + r);
                                    if (ct[t] < CAPP) {
                                        buf[(t * CAPP + ct[t]) * 512 + tid] = pk;
                                        ++ct[t];
                                    } else {
                                        const int row = t * 16 + col;
                                        const int sl = atomicAdd(&ovcnt[row], 1);
                                        if (sl < OCAP) ovf[row][sl] = pk;
                                    }
                                }
                            }
                        }
                    }
                }
            }
        }
    }
    cntT[0][wave][quad][col] = ct[0];
    cntT[1][wave][quad][col] = ct[1];
    cntT[2][wave][quad][col] = ct[2];
    __syncthreads();

    // ---------------- compaction (prefix over 32 segment counts) -----------
    {
        int bs[TIL] = {0, 0, 0}, tot[TIL] = {0, 0, 0};
        #pragma unroll 4
        for (int sg = 0; sg < SEGS; ++sg) {
            #pragma unroll
            for (int t = 0; t < TIL; ++t) {
                const int c = cntT[t][sg >> 2][sg & 3][col];
                if (sg < seg) bs[t] += c;
                tot[t] += c;
            }
        }
        #pragma unroll
        for (int t = 0; t < TIL; ++t)
            for (int p = 0; p < ct[t]; ++p)
                dense[(t * 16 + col) * DPAD + bs[t] + p] = buf[(t * CAPP + p) * 512 + tid];
        if (wave == 0 && quad == 0) {            // 16 lanes finalize 48 rows
            #pragma unroll
            for (int t = 0; t < TIL; ++t) {
                const int row = t * 16 + col;
                const int ov = ovcnt[row] < OCAP ? ovcnt[row] : OCAP;
                for (int o = 0; o < ov; ++o) dense[row * DPAD + tot[t] + o] = ovf[row][o];
                stotS[row] = tot[t] + ov;
            }
        }
    }
    __syncthreads();

    // ---------------- P3: merge (16 rows per pass, 3 passes) ---------------
    const double inv_den = s_inv_den;
    const int hw  = tid >> 5;                    // 0..15
    const int l32 = tid & 31;
    #pragma unroll 1
    for (int pass = 0; pass < 3; ++pass) {
        const int row  = pass * 16 + hw;
        const int grow = ibase + row;
        const int S    = stotS[row];
        finj[hw][l32] = grow;                    // default: self -> inert slot

        const unsigned* drow = dense + row * DPAD;
        if (S <= 96) rank_core<3>(drow, S, l32, finj[hw]);
        else         rank_core<9>(drow, S, l32, finj[hw]);
        __syncthreads();

        // fp64 refine (dot + both norms in one pass) + rank-16 + laplacian
        const int j = finj[hw][l32];
        const float4* xi = (const float4*)(coords + grow * DIM);
        const float4* xj = (const float4*)(coords + j * DIM);
        double dot = 0.0, sqi = 0.0, sqj = 0.0;
        #pragma unroll
        for (int q = 0; q < DIM / 4; ++q) {
            const float4 a = xi[q], b = xj[q];
            dot += (double)a.x * (double)b.x + (double)a.y * (double)b.y
                 + (double)a.z * (double)b.z + (double)a.w * (double)b.w;
            sqi += (double)a.x * (double)a.x + (double)a.y * (double)a.y
                 + (double)a.z * (double)a.z + (double)a.w * (double)a.w;
            sqj += (double)b.x * (double)b.x + (double)b.y * (double)b.y
                 + (double)b.z * (double)b.z + (double)b.w * (double)b.w;
        }
        double d2 = sqi + sqj + 1e-5 - 2.0 * dot;
        if (j == grow) d2 = 1e300;               // self / pad slots
        refd[hw][l32] = d2;
        __syncthreads();

        int rank = 0;
        #pragma unroll 1
        for (int m = 0; m < 32; ++m) {
            const double o = refd[hw][m];
            rank += (o < d2 || (o == d2 && m < l32)) ? 1 : 0;
        }
        const double wgt = exp(-d2 * inv_den);
        double contrib = (rank < KSEL && j != grow)
                       ? wgt * ((double)pot[j] - (double)pot[grow]) : 0.0;
        #pragma unroll
        for (int off = 1; off < 32; off <<= 1)
            contrib += __shfl_xor(contrib, off, 64);
        if (l32 == 0) out[grow] = (float)contrib;
        __syncthreads();                         // finj/refd reused next pass
    }
}

extern "C" void kernel_launch(void* const* d_in, const int* in_sizes, int n_in,
                              void* d_out, int out_size, void* d_ws, size_t ws_size,
                              hipStream_t stream)
{
    (void)in_sizes; (void)n_in; (void)out_size; (void)ws_size;
    const float* coords = (const float*)d_in[0];
    const float* pot    = (const float*)d_in[1];
    // d_in[2] is k (always 16, compiled in as KSEL)

    char* w = (char*)d_ws;
    float* s1 = (float*)w;                                   // [1]
    float* sx = (float*)(w + 4);                             // [DIM]
    int*   bar = (int*)(w + 512);                            // [1]
    __hip_bfloat16* chi  = (__hip_bfloat16*)(w + 1024);      // [N*64] 1.57 MB
    __hip_bfloat16* chiX = (__hip_bfloat16*)(w + 1024 + (size_t)N_PTS * DIM * 2);
                                                             // [N*8]  196.6 KB

    hipMemsetAsync((void*)w, 0, 1024, stream);               // s1+sx+bar
    mega_kernel<<<dim3(N_PTS / 48), dim3(512), 0, stream>>>(
        coords, pot, s1, sx, bar, chi, chiX, (float*)d_out);
}

// Round 14
// 198.379 us; speedup vs baseline: 1.0789x; 1.0789x over previous
//
#include <hip/hip_runtime.h>
#include <hip/hip_bf16.h>

#define N_PTS 12288
#define DIM   64
#define KSEL  16
#define EPS_F 1e-5f
#define TMARGIN 1.5f   // >= 2x bf16 cross-pair screen noise (~0.7); HW-validated r13

typedef __bf16 bf16x8 __attribute__((ext_vector_type(8)));
typedef float  f32x4  __attribute__((ext_vector_type(4)));

// Hand-rolled grid barrier (proven r7-r13; ~40us cheaper than cooperative
// launch). Safe: grid=256, 1 block/CU, co-resident by construction.
__device__ __forceinline__ void grid_sync(int* bar)
{
    __syncthreads();
    if (threadIdx.x == 0) {
        __hip_atomic_fetch_add(bar, 1, __ATOMIC_RELEASE, __HIP_MEMORY_SCOPE_AGENT);
        while (__hip_atomic_load(bar, __ATOMIC_ACQUIRE, __HIP_MEMORY_SCOPE_AGENT)
               < (int)gridDim.x)
            __builtin_amdgcn_s_sleep(2);
    }
    __syncthreads();
}

template<int CVN>
__device__ __forceinline__ void rank_core(const unsigned* __restrict__ drow,
                                          int S, int l32, int* __restrict__ fj)
{
    unsigned cv[CVN]; int rk[CVN];
    #pragma unroll
    for (int t = 0; t < CVN; ++t) {
        cv[t] = (t * 32 + l32 < S) ? drow[t * 32 + l32] : 0xFFFFFFFFu;
        rk[t] = 0;
    }
    #pragma unroll 4
    for (int m = 0; m < S; ++m) {
        const unsigned o = drow[m];
        #pragma unroll
        for (int t = 0; t < CVN; ++t) rk[t] += (o < cv[t]) ? 1 : 0;
    }
    #pragma unroll
    for (int t = 0; t < CVN; ++t)
        if (rk[t] < 32 && cv[t] != 0xFFFFFFFFu)
            fj[rk[t]] = (int)(cv[t] & 0x3FFFu);
}

// ---------------------------------------------------------------------------
// Round-12 kernel (measured 200.1us total / mega 154.5us — the session
// optimum, reproduced twice) with ONE free constant change: TMARGIN 2.0 ->
// 1.5 (zero added instructions; certification margin still >= 2x worst-case
// bf16 screen noise ~0.7, and TMARGIN=1.5 passed correctness in r13).
// r13's top-3 pool is REVERTED (it cost +10us VALU + 43% more LDS bank
// conflicts — more than its ~5-rank survivor saving was worth).
//
// Structure: grid 256 = 1 block/CU, 512 thr = 8 waves; block owns 48 i-rows
// x ALL j; wave owns a 1536-j slice in 96 steps of 16 j. K=96 MFMA folds
// the norms: acc = -d2/2, ONE compare per candidate.
//  P1: stride-2 sampled branchless per-lane top-2 -> pool 32segs x 2/row.
//      T[row] = 17th smallest pooled d2 + TMARGIN (17th absorbs diagonal).
//      Stride-2 keeps T TIGHT: r11 proved survivor count, not step count,
//      dominates P2 cost (~100 CU-cyc per extra survivor per row).
//  P2: full screen; per tile ONE max4 + wave-rare branch; branchless 4-slot
//      push when ct <= CAPP-4, else careful path + per-row overflow.
//  P3: compaction + rank-select top-32 + fp64 refine + rank-16 laplacian.
// ---------------------------------------------------------------------------
__global__ __launch_bounds__(512) void mega_kernel(
    const float* __restrict__ coords,
    const float* __restrict__ pot,
    float* __restrict__ s1,
    float* __restrict__ sx,
    int* __restrict__ bar,
    __hip_bfloat16* __restrict__ chi,
    __hip_bfloat16* __restrict__ chiX,
    float* __restrict__ out)
{
    constexpr int ROWS = 48, TIL = 3, CAPP = 8, OCAP = 16;
    constexpr int SEGS = 32;                     // 8 waves x 4 quads
    constexpr int DCAP = SEGS * CAPP + OCAP;     // 272 structural max/row
    constexpr int DPAD = DCAP + 1;               // 273
    constexpr int JSL  = N_PTS / 8;              // 1536
    constexpr int STEPS = JSL / 16;              // 96

    __shared__ float    colsh[8][64];
    __shared__ float    sqs8[8];
    __shared__ float    sqloc[ROWS];
    __shared__ float    pool[ROWS][64];
    __shared__ float    TrowS[ROWS];
    __shared__ unsigned buf[TIL * CAPP * 512];   // 49152 B
    __shared__ int      cntT[TIL][8][4][16];
    __shared__ unsigned dense[ROWS * DPAD];      // 52416 B
    __shared__ unsigned ovf[ROWS][OCAP];
    __shared__ int      ovcnt[ROWS];
    __shared__ int      stotS[ROWS];
    __shared__ int      finj[16][32];
    __shared__ double   refd[16][32];
    __shared__ double   s_inv_den;

    const int tid  = threadIdx.x;
    const int lane = tid & 63;
    const int wave = tid >> 6;                   // 0..7
    const int col  = lane & 15;
    const int quad = lane >> 4;
    const int ibase = (int)blockIdx.x * ROWS;

    // ---------------- phase A: stats for own 48 rows ----------------
    float colsum = 0.f, sqsum = 0.f;
    #pragma unroll 1
    for (int k = 0; k < 6; ++k) {
        const int rl = wave * 6 + k, gr = ibase + rl;
        const float x = coords[gr * DIM + lane];
        chi[gr * DIM + lane] = __float2bfloat16(x);
        colsum += x;
        float p = x * x;
        #pragma unroll
        for (int off = 32; off > 0; off >>= 1) p += __shfl_xor(p, off, 64);
        if (lane == 0) { sqloc[rl] = p; sqsum += p; }
        if (lane < 8) {
            const __hip_bfloat16 h = __float2bfloat16(p);
            const float lo = p - (float)h;
            __hip_bfloat16 v;
            if (lane == 0)      v = h;
            else if (lane == 1) v = __float2bfloat16(lo);
            else if (lane < 4)  v = __float2bfloat16(1.0f);
            else                v = __float2bfloat16(0.0f);
            chiX[gr * 8 + lane] = v;
        }
    }
    colsh[wave][lane] = colsum;
    if (lane == 0) sqs8[wave] = sqsum;
    if (tid < ROWS) ovcnt[tid] = 0;
    __syncthreads();
    if (wave == 0) {
        float c = 0.f;
        #pragma unroll
        for (int w8 = 0; w8 < 8; ++w8) c += colsh[w8][lane];
        atomicAdd(&sx[lane], c);
    }
    if (tid == 0) {
        float t = 0.f;
        #pragma unroll
        for (int w8 = 0; w8 < 8; ++w8) t += sqs8[w8];
        atomicAdd(s1, t);
    }
    grid_sync(bar);                              // chi/chiX + s1/sx final

    if (tid == 0) {
        double S1 = (double)s1[0], m2 = 0.0;
        for (int d = 0; d < DIM; ++d) { double t = (double)sx[d]; m2 += t * t; }
        const double NN = (double)N_PTS;
        s_inv_den = 1.0 / ((2.0 * NN * S1 - 2.0 * m2) / (NN * NN)
                           + 1e-5 + 1e6 / NN + 1e-5);
    }

    // ---------------- B-fragments (3 tiles x {lo, hi, ext}) ----------------
    const bf16x8* cp  = (const bf16x8*)chi;
    const bf16x8* cpX = (const bf16x8*)chiX;
    bf16x8 bA[TIL], bB[TIL], b2[TIL];
    #pragma unroll
    for (int t = 0; t < TIL; ++t) {
        const int it = ibase + t * 16 + col;
        bA[t] = cp[it * 8 + quad];
        bB[t] = cp[it * 8 + quad + 4];
        bf16x8 v;
        #pragma unroll
        for (int e = 0; e < 8; ++e) v[e] = (__bf16)0.0f;
        if (quad == 0) {                         // ext dims 0..3 live in quad 0
            const float bs = sqloc[t * 16 + col] + EPS_F;
            const __bf16 bh = (__bf16)(0.5f * bs);
            const __bf16 bl = (__bf16)(0.5f * bs - (float)bh);
            v[0] = (__bf16)(-0.5f); v[1] = (__bf16)(-0.5f);
            v[2] = (__bf16)(-(float)bh); v[3] = (__bf16)(-(float)bl);
        }
        b2[t] = v;
    }

    const int jw  = wave * JSL;
    const int seg = wave * 4 + quad;             // 0..31

    auto LD = [&](int s, bf16x8& A0, bf16x8& A1, bf16x8& A2) {
        const int ar = jw + s * 16 + col;
        A0 = cp[ar * 8 + quad];
        A1 = cp[ar * 8 + quad + 4];
        A2 = cpX[ar];                            // quads 1-3 killed by b2 zeros
    };
    auto MFMA3 = [&](const bf16x8& A0, const bf16x8& A1, const bf16x8& A2,
                     f32x4 (&acc)[TIL]) {
        #pragma unroll
        for (int t = 0; t < TIL; ++t) {
            f32x4 a = {0.f, 0.f, 0.f, 0.f};
            a = __builtin_amdgcn_mfma_f32_16x16x32_bf16(A0, bA[t], a, 0, 0, 0);
            a = __builtin_amdgcn_mfma_f32_16x16x32_bf16(A1, bB[t], a, 0, 0, 0);
            a = __builtin_amdgcn_mfma_f32_16x16x32_bf16(A2, b2[t], a, 0, 0, 0);
            acc[t] = a;                          // acc = -d2/2
        }
    };

    // ---------------- P1: stride-2 sampled top-2, 4-deep prefetch ----------
    float m0[TIL], m1[TIL];
    #pragma unroll
    for (int t = 0; t < TIL; ++t) { m0[t] = -1e30f; m1[t] = -1e30f; }
    {
        bf16x8 A0[4], A1[4], A2[4];
        #pragma unroll
        for (int p = 0; p < 4; ++p) LD(2 * p, A0[p], A1[p], A2[p]);
        #pragma unroll 1
        for (int k = 0; k < STEPS / 2; k += 4) {
            #pragma unroll
            for (int p = 0; p < 4; ++p) {
                f32x4 acc[TIL];
                MFMA3(A0[p], A1[p], A2[p], acc);
                int sn = 2 * (k + p + 4);
                sn = (sn < STEPS) ? sn : 0;      // harmless reload at the tail
                LD(sn, A0[p], A1[p], A2[p]);
                #pragma unroll
                for (int t = 0; t < TIL; ++t) {
                    #pragma unroll
                    for (int r = 0; r < 4; ++r) {
                        const float da = acc[t][r];
                        const bool g = da > m0[t];
                        m1[t] = g ? m0[t] : fmaxf(m1[t], da);
                        m0[t] = fmaxf(m0[t], da);
                    }
                }
            }
        }
    }
    #pragma unroll
    for (int t = 0; t < TIL; ++t) {              // two smallest d2 per bucket
        pool[t * 16 + col][seg * 2]     = -2.f * m0[t];
        pool[t * 16 + col][seg * 2 + 1] = -2.f * m1[t];
    }
    __syncthreads();

    // T = 17th smallest of 64 pooled d2 (+margin); wave -> rows 6w..6w+5
    #pragma unroll 1
    for (int rr = 0; rr < 6; ++rr) {
        const int row = wave * 6 + rr;
        const float val = pool[row][lane];
        int rank = 0;
        #pragma unroll 8
        for (int m = 0; m < 64; ++m) {
            const float o = pool[row][m];
            rank += (o < val || (o == val && m < lane)) ? 1 : 0;
        }
        if (rank == 16) TrowS[row] = val + TMARGIN;
    }
    __syncthreads();

    float tthr[TIL];
    #pragma unroll
    for (int t = 0; t < TIL; ++t) tthr[t] = -0.5f * TrowS[t * 16 + col];

    // ---------------- P2: full screen, branch-light epilogue ---------------
    int ct[TIL] = {0, 0, 0};
    {
        bf16x8 A0[4], A1[4], A2[4];
        #pragma unroll
        for (int p = 0; p < 4; ++p) LD(p, A0[p], A1[p], A2[p]);
        #pragma unroll 1
        for (int s = 0; s < STEPS; s += 4) {
            #pragma unroll
            for (int p = 0; p < 4; ++p) {
                f32x4 acc[TIL];
                MFMA3(A0[p], A1[p], A2[p], acc);
                int sn = s + p + 4;
                sn = (sn < STEPS) ? sn : 0;      // harmless reload at the tail
                LD(sn, A0[p], A1[p], A2[p]);

                const int jq = jw + (s + p) * 16 + quad * 4;
                #pragma unroll
                for (int t = 0; t < TIL; ++t) {
                    const float mx = fmaxf(fmaxf(acc[t][0], acc[t][1]),
                                           fmaxf(acc[t][2], acc[t][3]));
                    if (mx > tthr[t]) {          // wave-rare tile gate
                        if (__all(ct[t] <= CAPP - 4)) {
                            // branchless dense push: write@ct, ct += hit;
                            // misses overwritten by the next write.
                            #pragma unroll
                            for (int r = 0; r < 4; ++r) {
                                const float d2 = -2.f * acc[t][r];
                                const unsigned pk =
                                    (__float_as_uint(d2) & 0xFFFFC000u)
                                    | (unsigned)(jq + r);
                                buf[(t * CAPP + ct[t]) * 512 + tid] = pk;
                                ct[t] += (acc[t][r] > tthr[t]) ? 1 : 0;
                            }
                        } else {                 // near-full: careful + ovf
                            #pragma unroll
                            for (int r = 0; r < 4; ++r) {
                                if (acc[t][r] > tthr[t]) {
                                    const float d2 = -2.f * acc[t][r];
                                    const unsigned pk =
                                        (__float_as_uint(d2) & 0xFFFFC000u)
                                        | (unsigned)(jq + r);
                                    if (ct[t] < CAPP) {
                                        buf[(t * CAPP + ct[t]) * 512 + tid] = pk;
                                        ++ct[t];
                                    } else {
                                        const int row = t * 16 + col;
                                        const int sl = atomicAdd(&ovcnt[row], 1);
                                        if (sl < OCAP) ovf[row][sl] = pk;
                                    }
                                }
                            }
                        }
                    }
                }
            }
        }
    }
    cntT[0][wave][quad][col] = ct[0];
    cntT[1][wave][quad][col] = ct[1];
    cntT[2][wave][quad][col] = ct[2];
    __syncthreads();

    // ---------------- compaction (prefix over 32 segment counts) -----------
    {
        int bs[TIL] = {0, 0, 0}, tot[TIL] = {0, 0, 0};
        #pragma unroll 4
        for (int sg = 0; sg < SEGS; ++sg) {
            #pragma unroll
            for (int t = 0; t < TIL; ++t) {
                const int c = cntT[t][sg >> 2][sg & 3][col];
                if (sg < seg) bs[t] += c;
                tot[t] += c;
            }
        }
        #pragma unroll
        for (int t = 0; t < TIL; ++t)
            for (int p = 0; p < ct[t]; ++p)
                dense[(t * 16 + col) * DPAD + bs[t] + p] = buf[(t * CAPP + p) * 512 + tid];
        if (wave == 0 && quad == 0) {            // 16 lanes finalize 48 rows
            #pragma unroll
            for (int t = 0; t < TIL; ++t) {
                const int row = t * 16 + col;
                const int ov = ovcnt[row] < OCAP ? ovcnt[row] : OCAP;
                for (int o = 0; o < ov; ++o) dense[row * DPAD + tot[t] + o] = ovf[row][o];
                stotS[row] = tot[t] + ov;
            }
        }
    }
    __syncthreads();

    // ---------------- P3: merge (16 rows per pass, 3 passes) ---------------
    const double inv_den = s_inv_den;
    const int hw  = tid >> 5;                    // 0..15
    const int l32 = tid & 31;
    #pragma unroll 1
    for (int pass = 0; pass < 3; ++pass) {
        const int row  = pass * 16 + hw;
        const int grow = ibase + row;
        const int S    = stotS[row];
        finj[hw][l32] = grow;                    // default: self -> inert slot

        const unsigned* drow = dense + row * DPAD;
        if (S <= 96) rank_core<3>(drow, S, l32, finj[hw]);
        else         rank_core<9>(drow, S, l32, finj[hw]);
        __syncthreads();

        // fp64 refine (dot + both norms in one pass) + rank-16 + laplacian
        const int j = finj[hw][l32];
        const float4* xi = (const float4*)(coords + grow * DIM);
        const float4* xj = (const float4*)(coords + j * DIM);
        double dot = 0.0, sqi = 0.0, sqj = 0.0;
        #pragma unroll
        for (int q = 0; q < DIM / 4; ++q) {
            const float4 a = xi[q], b = xj[q];
            dot += (double)a.x * (double)b.x + (double)a.y * (double)b.y
                 + (double)a.z * (double)b.z + (double)a.w * (double)b.w;
            sqi += (double)a.x * (double)a.x + (double)a.y * (double)a.y
                 + (double)a.z * (double)a.z + (double)a.w * (double)a.w;
            sqj += (double)b.x * (double)b.x + (double)b.y * (double)b.y
                 + (double)b.z * (double)b.z + (double)b.w * (double)b.w;
        }
        double d2 = sqi + sqj + 1e-5 - 2.0 * dot;
        if (j == grow) d2 = 1e300;               // self / pad slots
        refd[hw][l32] = d2;
        __syncthreads();

        int rank = 0;
        #pragma unroll 1
        for (int m = 0; m < 32; ++m) {
            const double o = refd[hw][m];
            rank += (o < d2 || (o == d2 && m < l32)) ? 1 : 0;
        }
        const double wgt = exp(-d2 * inv_den);
        double contrib = (rank < KSEL && j != grow)
                       ? wgt * ((double)pot[j] - (double)pot[grow]) : 0.0;
        #pragma unroll
        for (int off = 1; off < 32; off <<= 1)
            contrib += __shfl_xor(contrib, off, 64);
        if (l32 == 0) out[grow] = (float)contrib;
        __syncthreads();                         // finj/refd reused next pass
    }
}

extern "C" void kernel_launch(void* const* d_in, const int* in_sizes, int n_in,
                              void* d_out, int out_size, void* d_ws, size_t ws_size,
                              hipStream_t stream)
{
    (void)in_sizes; (void)n_in; (void)out_size; (void)ws_size;
    const float* coords = (const float*)d_in[0];
    const float* pot    = (const float*)d_in[1];
    // d_in[2] is k (always 16, compiled in as KSEL)

    char* w = (char*)d_ws;
    float* s1 = (float*)w;                                   // [1]
    float* sx = (float*)(w + 4);                             // [DIM]
    int*   bar = (int*)(w + 512);                            // [1]
    __hip_bfloat16* chi  = (__hip_bfloat16*)(w + 1024);      // [N*64] 1.57 MB
    __hip_bfloat16* chiX = (__hip_bfloat16*)(w + 1024 + (size_t)N_PTS * DIM * 2);
                                                             // [N*8]  196.6 KB

    hipMemsetAsync((void*)w, 0, 1024, stream);               // s1+sx+bar
    mega_kernel<<<dim3(N_PTS / 48), dim3(512), 0, stream>>>(
        coords, pot, s1, sx, bar, chi, chiX, (float*)d_out);
}